// Round 4
// baseline (843.487 us; speedup 1.0000x reference)
//
#include <hip/hip_runtime.h>
#include <cstdint>

// Rule 30, 2 states, r=1, wrap. idx = L + 2C + 4R, table = bits of 30
// reduces to: new = R ^ (C | L).
//
// B=16 rows, W=2048 cells, T=1024 steps, history = T+1 states.
// Output: int32 [B][T+1][W] (reference returns uint8 -> harness int32).
//
// Round-4 design: ONE kernel, producer-consumer overlap.
//  - blocks 0..15  : producers. Wave 0 evolves row b (64 lanes x u32 words,
//    ghost-zone window trick: 1 shuffle pair per 16 steps, rule applied to a
//    64-bit window as win = (win>>1) ^ (win | (win<<1))).
//    Packed states go to ws via AGENT-scope atomic stores (cross-XCD visible),
//    layout pk[b][r][j][word] (r = 16-step block, j = step in block) so each
//    step's store is one coalesced 256B wave-store.
//  - blocks 16..1023: consumers. Spin on per-chunk 64-bit exact-match magic
//    flags, then expand one chunk (16 states x 2048 cells) of packed bits to
//    int32 output (contiguous 131KB region per chunk).
//  - flag[r] published with lag-one + s_waitcnt vmcnt(16): orders the flag
//    after block r's stores WITHOUT ever draining the store queue to 0.
//  - Replay-safe: stale flags from a previous replay match exactly and gate
//    reads of identical (deterministic) pk data; 0xAA-poisoned ws never
//    matches (2^-64); all blocks resident by capacity -> no spin deadlock.

#define B 16
#define W 2048
#define T_ITERS 1024
#define HIST (T_ITERS + 1)
#define LANES 64
#define K_STEPS 16
#define RBLKS (T_ITERS / K_STEPS)      // 64
#define NCHUNK (RBLKS * B + B)         // 1024 main + 16 t0 chunks = 1040
#define GRID 1024
#define FLAG_MAGIC 0xC0FFEE5EED000000ULL

typedef unsigned long long u64;

__device__ __forceinline__ void expand_nib(int4* o, unsigned nib) {
    int4 f;
    f.x = (int)(nib & 1u);
    f.y = (int)((nib >> 1) & 1u);
    f.z = (int)((nib >> 2) & 1u);
    f.w = (int)((nib >> 3) & 1u);
    *o = f;
}

__global__ __launch_bounds__(256) void ca_mega(const float* __restrict__ x,
                                               int4* __restrict__ out,
                                               unsigned* __restrict__ pk,   // [16][64][16][64] u32
                                               unsigned* __restrict__ pk0,  // [16][64] u32
                                               u64* __restrict__ flags) {   // [1040]
    const int blk = blockIdx.x;
    const int tid = threadIdx.x;

    if (blk < B) {
        // ---------------- producer: evolve row blk ----------------
        if (tid >= 64) return;          // wave 0 only
        const int b = blk, l = tid;

        const float4* xv = (const float4*)(x + (size_t)b * W + (size_t)l * 32);
        unsigned m = 0;
        #pragma unroll
        for (int i = 0; i < 8; ++i) {
            float4 v = xv[i];
            unsigned n = (v.x >= 0.5f ? 1u : 0u) | (v.y >= 0.5f ? 2u : 0u) |
                         (v.z >= 0.5f ? 4u : 0u) | (v.w >= 0.5f ? 8u : 0u);
            m |= n << (4 * i);
        }

        // t = 0 chunk
        __hip_atomic_store(&pk0[b * LANES + l], m, __ATOMIC_RELAXED,
                           __HIP_MEMORY_SCOPE_AGENT);
        asm volatile("s_waitcnt vmcnt(0)" ::: "memory");
        if (l == 0)
            __hip_atomic_store(&flags[RBLKS * B + b],
                               FLAG_MAGIC + (u64)(RBLKS * B + b),
                               __ATOMIC_RELAXED, __HIP_MEMORY_SCOPE_AGENT);

        unsigned* pb = pk + ((size_t)b * RBLKS) * (K_STEPS * LANES) + l;
        for (int r = 0; r < RBLKS; ++r) {
            unsigned left  = __shfl(m, (l + LANES - 1) & (LANES - 1));
            unsigned right = __shfl(m, (l + 1) & (LANES - 1));
            u64 win = ((u64)(left >> 16)) | ((u64)m << 16) | ((u64)right << 48);
            unsigned* pr = pb + r * (K_STEPS * LANES);
            #pragma unroll
            for (int j = 0; j < K_STEPS; ++j) {
                win = (win >> 1) ^ (win | (win << 1));   // rule 30, all 64 bits
                m = (unsigned)(win >> 16);               // middle 32, valid j<16... j<=15
                __hip_atomic_store(pr + j * LANES, m, __ATOMIC_RELAXED,
                                   __HIP_MEMORY_SCOPE_AGENT);
            }
            // all stores of blocks <= r-1 are complete once <=16 remain in
            // flight (the 16 just issued). Publish flag for r-1 (lag one).
            asm volatile("s_waitcnt vmcnt(16)" ::: "memory");
            if (l == 0 && r > 0) {
                int q = (r - 1) * B + b;
                __hip_atomic_store(&flags[q], FLAG_MAGIC + (u64)q,
                                   __ATOMIC_RELAXED, __HIP_MEMORY_SCOPE_AGENT);
            }
        }
        asm volatile("s_waitcnt vmcnt(0)" ::: "memory");
        if (l == 0) {
            int q = (RBLKS - 1) * B + b;
            __hip_atomic_store(&flags[q], FLAG_MAGIC + (u64)q,
                               __ATOMIC_RELAXED, __HIP_MEMORY_SCOPE_AGENT);
        }
    } else {
        // ---------------- consumer: expand chunks ----------------
        const int nc = (int)gridDim.x - B;     // 1008
        const int k = blk - B;
        for (int pass = 0; pass < 2; ++pass) {
            int q = k + pass * nc;
            if (q >= NCHUNK) break;
            const u64 want = FLAG_MAGIC + (u64)q;
            while (__hip_atomic_load(&flags[q], __ATOMIC_ACQUIRE,
                                     __HIP_MEMORY_SCOPE_AGENT) != want)
                __builtin_amdgcn_s_sleep(2);

            if (q < RBLKS * B) {
                const int r = q >> 4, b = q & 15;
                const unsigned* src = pk + ((size_t)(b * RBLKS + r)) * (K_STEPS * LANES);
                int4* o = out + (((size_t)b * HIST + (size_t)(K_STEPS * r + 1)) << 9);
                for (int i = tid; i < K_STEPS * 512; i += 256) {
                    int j = i >> 9, pos = i & 511, w = pos >> 3;
                    unsigned u = __hip_atomic_load(src + j * LANES + w,
                                                   __ATOMIC_RELAXED,
                                                   __HIP_MEMORY_SCOPE_AGENT);
                    expand_nib(o + i, (u >> ((pos & 7) * 4)) & 0xFu);
                }
            } else {
                const int b = q - RBLKS * B;               // t = 0 chunk
                const unsigned* src = pk0 + b * LANES;
                int4* o = out + (((size_t)b * HIST) << 9);
                for (int i = tid; i < 512; i += 256) {
                    int w = i >> 3;
                    unsigned u = __hip_atomic_load(src + w, __ATOMIC_RELAXED,
                                                   __HIP_MEMORY_SCOPE_AGENT);
                    expand_nib(o + i, (u >> ((i & 7) * 4)) & 0xFu);
                }
            }
        }
    }
}

// ---------------- fallback 1: round-3 two-kernel path ----------------
__global__ __launch_bounds__(64) void ca_evolve(const float* __restrict__ x,
                                                unsigned* __restrict__ pk) {
    const int b = blockIdx.x;
    const int l = threadIdx.x;
    const float4* xv = (const float4*)(x + (size_t)b * W + (size_t)l * 32);
    unsigned m = 0;
    #pragma unroll
    for (int i = 0; i < 8; ++i) {
        float4 v = xv[i];
        unsigned n = (v.x >= 0.5f ? 1u : 0u) | (v.y >= 0.5f ? 2u : 0u) |
                     (v.z >= 0.5f ? 4u : 0u) | (v.w >= 0.5f ? 8u : 0u);
        m |= n << (4 * i);
    }
    unsigned* p = pk + (size_t)b * HIST * LANES + l;
    *p = m;
    p += LANES;
    for (int r = 0; r < RBLKS; ++r) {
        unsigned left  = __shfl(m, (l + LANES - 1) & (LANES - 1));
        unsigned right = __shfl(m, (l + 1) & (LANES - 1));
        u64 win = ((u64)(left >> 16)) | ((u64)m << 16) | ((u64)right << 48);
        #pragma unroll
        for (int j = 0; j < K_STEPS; ++j) {
            win = (win >> 1) ^ (win | (win << 1));
            m = (unsigned)(win >> 16);
            *p = m;
            p += LANES;
        }
    }
}

__global__ __launch_bounds__(256) void ca_expand(const unsigned char* __restrict__ pk,
                                                 int4* __restrict__ out, int n4) {
    int i = blockIdx.x * 256 + threadIdx.x;
    if (i >= n4) return;
    unsigned byte = pk[i >> 1];
    expand_nib(&out[i], (byte >> ((i & 1) * 4)) & 0xFu);
}

// ---------------- fallback 2: fused direct path (tiny ws) ----------------
__global__ __launch_bounds__(64) void ca_fused(const float* __restrict__ x,
                                               int* __restrict__ out) {
    const int b = blockIdx.x;
    const int l = threadIdx.x;
    const float4* xv = (const float4*)(x + (size_t)b * W + (size_t)l * 32);
    unsigned m = 0;
    #pragma unroll
    for (int i = 0; i < 8; ++i) {
        float4 v = xv[i];
        unsigned n = (v.x >= 0.5f ? 1u : 0u) | (v.y >= 0.5f ? 2u : 0u) |
                     (v.z >= 0.5f ? 4u : 0u) | (v.w >= 0.5f ? 8u : 0u);
        m |= n << (4 * i);
    }
    int* o = out + (size_t)b * HIST * W + (size_t)l * 32;
    #pragma unroll
    for (int c = 0; c < 32; ++c) o[c] = (int)((m >> c) & 1u);
    o += W;
    for (int r = 0; r < RBLKS; ++r) {
        unsigned left  = __shfl(m, (l + LANES - 1) & (LANES - 1));
        unsigned right = __shfl(m, (l + 1) & (LANES - 1));
        u64 win = ((u64)(left >> 16)) | ((u64)m << 16) | ((u64)right << 48);
        #pragma unroll
        for (int j = 0; j < K_STEPS; ++j) {
            win = (win >> 1) ^ (win | (win << 1));
            m = (unsigned)(win >> 16);
            #pragma unroll
            for (int c = 0; c < 32; ++c) o[c] = (int)((m >> c) & 1u);
            o += W;
        }
    }
}

extern "C" void kernel_launch(void* const* d_in, const int* in_sizes, int n_in,
                              void* d_out, int out_size, void* d_ws, size_t ws_size,
                              hipStream_t stream) {
    const float* x = (const float*)d_in[0];

    const size_t pk_u32   = (size_t)B * RBLKS * K_STEPS * LANES;   // 1,048,576
    const size_t pk0_u32  = (size_t)B * LANES;                     // 1,024
    const size_t need_mega = (pk_u32 + pk0_u32) * 4 + NCHUNK * 8;  // ~4.21 MB
    const size_t need_two  = (size_t)B * HIST * LANES * 4;         // ~4.20 MB

    if (ws_size >= need_mega) {
        unsigned* pk   = (unsigned*)d_ws;
        unsigned* pk0  = pk + pk_u32;
        u64*      flags = (u64*)(pk0 + pk0_u32);
        ca_mega<<<GRID, 256, 0, stream>>>(x, (int4*)d_out, pk, pk0, flags);
    } else if (ws_size >= need_two) {
        unsigned* pk = (unsigned*)d_ws;
        ca_evolve<<<B, 64, 0, stream>>>(x, pk);
        const int n4 = B * HIST * W / 4;
        ca_expand<<<(n4 + 255) / 256, 256, 0, stream>>>((const unsigned char*)pk,
                                                        (int4*)d_out, n4);
    } else {
        ca_fused<<<B, 64, 0, stream>>>(x, (int*)d_out);
    }
}

// Round 5
// 52.445 us; speedup vs baseline: 16.0833x; 16.0833x over previous
//
#include <hip/hip_runtime.h>
#include <cstdint>

// Rule 30, 2 states, r=1, wrap. idx = L + 2C + 4R, table = bits of 30
// reduces to: new = R ^ (C | L).
//
// B=16 rows, W=2048 cells, T=1024 steps, history = T+1 states.
// Output: int32 [B][T+1][W] (reference returns uint8 -> harness int32).
//
// Round-5 design: REDUNDANT EVOLUTION, fully independent blocks.
//   grid = 16 rows x 64 time-chunks = 1024 blocks, 1 wave each.
//   Block (b, r): re-runs row b's bit-packed chain from t=0 through step
//   (r+1)*16 entirely in registers (ghost-zone window: one 32-bit shuffle
//   pair per 16 steps; rule on the 64-bit window is
//   win = (win>>1) ^ (win | (win<<1)), middle 32 bits valid 16 steps).
//   The 16 states of its own chunk go to LDS (4 KB), then get expanded to
//   the block's private 131 KB output slice as contiguous int4 wave-stores.
//   No workspace, no flags, no inter-block communication: the round-4
//   spin-flag FETCH storm (2.4 GB) is structurally impossible here.
//   Chain cost: ~12 cy/step of pure VALU; longest block ~8 us, hidden
//   under the 21 us aggregate write stream.

#define B 16
#define W 2048
#define T_ITERS 1024
#define HIST (T_ITERS + 1)
#define LANES 64
#define K_STEPS 16
#define RBLKS (T_ITERS / K_STEPS)      // 64 chunks
#define ROW_I4 (W / 4)                 // 512 int4 per state row

typedef unsigned long long u64;

__global__ __launch_bounds__(64) void ca_redundant(const float* __restrict__ x,
                                                   int4* __restrict__ out) {
    __shared__ unsigned st[K_STEPS][LANES];   // chunk's 16 packed states
    __shared__ unsigned st0[LANES];           // packed t=0 (used by r==0 only)

    const int blk = blockIdx.x;
    const int b = blk & (B - 1);              // row
    const int r = blk >> 4;                   // time-chunk 0..63
    const int l = threadIdx.x;                // lane, owns cells [32l, 32l+32)

    // ---- pack 32 thresholded floats into a u32 (bit i = cell 32l+i) ----
    const float4* xv = (const float4*)(x + (size_t)b * W + (size_t)l * 32);
    unsigned m = 0;
    #pragma unroll
    for (int i = 0; i < 8; ++i) {
        float4 v = xv[i];
        unsigned n = (v.x >= 0.5f ? 1u : 0u) | (v.y >= 0.5f ? 2u : 0u) |
                     (v.z >= 0.5f ? 4u : 0u) | (v.w >= 0.5f ? 8u : 0u);
        m |= n << (4 * i);
    }
    if (r == 0) st0[l] = m;

    // ---- chain: r+1 exchange groups of 16 steps; save only group r ----
    for (int g = 0; g <= r; ++g) {
        unsigned left  = __shfl(m, (l + LANES - 1) & (LANES - 1));
        unsigned right = __shfl(m, (l + 1) & (LANES - 1));
        // window bit p = cell (32l - 16 + p); bits [16..47] = own cells
        u64 win = ((u64)(left >> 16)) | ((u64)m << 16) | ((u64)right << 48);
        if (g < r) {
            #pragma unroll
            for (int j = 0; j < K_STEPS; ++j)
                win = (win >> 1) ^ (win | (win << 1));   // rule 30, 64 bits
            m = (unsigned)(win >> 16);                   // valid after 16 steps
        } else {
            #pragma unroll
            for (int j = 0; j < K_STEPS; ++j) {
                win = (win >> 1) ^ (win | (win << 1));
                m = (unsigned)(win >> 16);               // valid for j<=15
                st[j][l] = m;                            // 2 lanes/bank: free
            }
        }
    }
    __syncthreads();   // single wave: just drains lgkmcnt

    // ---- expand: contiguous int4 stores; lane l writes int4 c = l + 64i ----
    // nibble c of a packed row lives in word c>>3 = (l>>3)+8i, shift (l&7)*4
    // (constant per lane). LDS reads: 8 lanes broadcast per word, 8 words per
    // i across 8 banks -> conflict-free.
    if (r == 0) {
        int4* o = out + ((size_t)b * HIST) * ROW_I4;     // t = 0 row
        #pragma unroll
        for (int i = 0; i < 8; ++i) {
            unsigned u = st0[(l >> 3) + 8 * i];
            unsigned nib = (u >> ((l & 7) * 4)) & 0xFu;
            int4 f;
            f.x = (int)(nib & 1u);
            f.y = (int)((nib >> 1) & 1u);
            f.z = (int)((nib >> 2) & 1u);
            f.w = (int)((nib >> 3) & 1u);
            o[l + 64 * i] = f;
        }
    }
    for (int j = 0; j < K_STEPS; ++j) {
        int4* o = out + ((size_t)b * HIST + (size_t)(r * K_STEPS + 1 + j)) * ROW_I4;
        #pragma unroll
        for (int i = 0; i < 8; ++i) {
            unsigned u = st[j][(l >> 3) + 8 * i];
            unsigned nib = (u >> ((l & 7) * 4)) & 0xFu;
            int4 f;
            f.x = (int)(nib & 1u);
            f.y = (int)((nib >> 1) & 1u);
            f.z = (int)((nib >> 2) & 1u);
            f.w = (int)((nib >> 3) & 1u);
            o[l + 64 * i] = f;
        }
    }
}

extern "C" void kernel_launch(void* const* d_in, const int* in_sizes, int n_in,
                              void* d_out, int out_size, void* d_ws, size_t ws_size,
                              hipStream_t stream) {
    const float* x = (const float*)d_in[0];
    // 1024 independent blocks; no workspace needed.
    ca_redundant<<<B * RBLKS, 64, 0, stream>>>(x, (int4*)d_out);
}

// Round 6
// 33.276 us; speedup vs baseline: 25.3484x; 1.5761x over previous
//
#include <hip/hip_runtime.h>
#include <cstdint>

// Rule 30, 2 states, r=1, wrap. idx = L + 2C + 4R, table = bits of 30
// reduces to: new = R ^ (C | L).
//
// B=16 rows, W=2048 cells, T=1024 steps, history = T+1 states.
// Output: int32 [B][T+1][W] (reference returns uint8 -> harness int32).
//
// Round-6 = round-5 structure + NON-TEMPORAL output stores.
//   Round-5 post-mortem: kernel sustained only 2.6 TB/s writing 134 MB while
//   rocclr's fill kernel sustains 6.5 TB/s on the same buffer -> the limiter
//   is L2 write-allocate churn on a one-pass 134 MB store stream, not the
//   compute structure. __builtin_nontemporal_store sets the nt bit
//   (bypasses L2 allocation), matching the fill kernel's store path.
//
// Structure (unchanged, proven correct in round 5):
//   grid = 16 rows x 64 time-chunks = 1024 independent single-wave blocks.
//   Block (b, r) re-runs row b's bit-packed chain from t=0 through step
//   (r+1)*16 in registers (ghost-zone window, 1 shuffle pair / 16 steps;
//   rule on the 64-bit window: win = (win>>1) ^ (win | (win<<1))), parks
//   its 16 states in LDS, then expands to its private 131 KB output slice
//   with contiguous 1 KB wave-stores. No workspace, no inter-block comms.

#define B 16
#define W 2048
#define T_ITERS 1024
#define HIST (T_ITERS + 1)
#define LANES 64
#define K_STEPS 16
#define RBLKS (T_ITERS / K_STEPS)      // 64 chunks
#define ROW_I4 (W / 4)                 // 512 int4 per state row

typedef unsigned long long u64;
typedef int v4i __attribute__((ext_vector_type(4)));   // builtin-friendly int4

__device__ __forceinline__ void store_nib_nt(v4i* o, unsigned nib) {
    v4i f;
    f.x = (int)(nib & 1u);
    f.y = (int)((nib >> 1) & 1u);
    f.z = (int)((nib >> 2) & 1u);
    f.w = (int)((nib >> 3) & 1u);
    __builtin_nontemporal_store(f, o);   // global_store_dwordx4 ... nt
}

__global__ __launch_bounds__(64) void ca_redundant(const float* __restrict__ x,
                                                   v4i* __restrict__ out) {
    __shared__ unsigned st[K_STEPS][LANES];   // chunk's 16 packed states
    __shared__ unsigned st0[LANES];           // packed t=0 (r==0 only)

    const int blk = blockIdx.x;
    const int b = blk & (B - 1);              // row
    const int r = blk >> 4;                   // time-chunk 0..63
    const int l = threadIdx.x;                // lane, owns cells [32l, 32l+32)

    // ---- pack 32 thresholded floats into a u32 (bit i = cell 32l+i) ----
    const float4* xv = (const float4*)(x + (size_t)b * W + (size_t)l * 32);
    unsigned m = 0;
    #pragma unroll
    for (int i = 0; i < 8; ++i) {
        float4 v = xv[i];
        unsigned n = (v.x >= 0.5f ? 1u : 0u) | (v.y >= 0.5f ? 2u : 0u) |
                     (v.z >= 0.5f ? 4u : 0u) | (v.w >= 0.5f ? 8u : 0u);
        m |= n << (4 * i);
    }
    if (r == 0) st0[l] = m;

    // ---- chain: r+1 exchange groups of 16 steps; save only group r ----
    for (int g = 0; g <= r; ++g) {
        unsigned left  = __shfl(m, (l + LANES - 1) & (LANES - 1));
        unsigned right = __shfl(m, (l + 1) & (LANES - 1));
        // window bit p = cell (32l - 16 + p); bits [16..47] = own cells
        u64 win = ((u64)(left >> 16)) | ((u64)m << 16) | ((u64)right << 48);
        if (g < r) {
            #pragma unroll
            for (int j = 0; j < K_STEPS; ++j)
                win = (win >> 1) ^ (win | (win << 1));   // rule 30, 64 bits
            m = (unsigned)(win >> 16);                   // valid after 16 steps
        } else {
            #pragma unroll
            for (int j = 0; j < K_STEPS; ++j) {
                win = (win >> 1) ^ (win | (win << 1));
                m = (unsigned)(win >> 16);               // valid for j<=15
                st[j][l] = m;                            // 2 lanes/bank: free
            }
        }
    }
    __syncthreads();   // single wave: drains lgkmcnt

    // ---- expand: contiguous nt int4 stores; lane l writes int4 c = l+64i ----
    // nibble c of a packed row lives in word c>>3 = (l>>3)+8i, shift (l&7)*4.
    // LDS reads: 8 lanes broadcast per word, 8 words across 8 banks -> clean.
    if (r == 0) {
        v4i* o = out + ((size_t)b * HIST) * ROW_I4;      // t = 0 row
        #pragma unroll
        for (int i = 0; i < 8; ++i) {
            unsigned u = st0[(l >> 3) + 8 * i];
            store_nib_nt(o + l + 64 * i, (u >> ((l & 7) * 4)) & 0xFu);
        }
    }
    for (int j = 0; j < K_STEPS; ++j) {
        v4i* o = out + ((size_t)b * HIST + (size_t)(r * K_STEPS + 1 + j)) * ROW_I4;
        #pragma unroll
        for (int i = 0; i < 8; ++i) {
            unsigned u = st[j][(l >> 3) + 8 * i];
            store_nib_nt(o + l + 64 * i, (u >> ((l & 7) * 4)) & 0xFu);
        }
    }
}

extern "C" void kernel_launch(void* const* d_in, const int* in_sizes, int n_in,
                              void* d_out, int out_size, void* d_ws, size_t ws_size,
                              hipStream_t stream) {
    const float* x = (const float*)d_in[0];
    // 1024 independent blocks; no workspace needed.
    ca_redundant<<<B * RBLKS, 64, 0, stream>>>(x, (v4i*)d_out);
}